// Round 18
// baseline (118.938 us; speedup 1.0000x reference)
//
#include <hip/hip_runtime.h>

#define WS 9
#define PS 7
#define KMAX 10
#define STRIDE0 4
#define NEPOCHS 100
#define BB 1
#define TT 5
#define CC 3
#define HH 256
#define WW 256
#define QQ (TT * 64 * 64)             // 20480
#define NOFF 243
#define SELF_IDX 40                   // (WS/2)*WS + WS/2
#define HW (HH * WW)
#define TSTR 20                       // tile row stride: 80B = b128-aligned, conflict-free

typedef float f4a __attribute__((ext_vector_type(4)));              // aligned LDS/reg
typedef float f4u __attribute__((ext_vector_type(4), aligned(4)));  // 4B-aligned global
typedef float f2  __attribute__((ext_vector_type(2)));              // packed pair
typedef long long s64;

static __device__ __forceinline__ int k_eff_from_epoch(int ep) {
    int k = (int)((double)KMAX * ((double)(NEPOCHS - ep) / (double)NEPOCHS));
    return k < 2 ? 2 : k;
}

template <int CTRL>
static __device__ __forceinline__ float dpp_add(float v) {
    const int x = __float_as_int(v);
    const int y = __builtin_amdgcn_update_dpp(0, x, CTRL, 0xF, 0xF, true);
    return v + __int_as_float(y);
}
static __device__ __forceinline__ float swz4_add(float v) {
    const int x = __float_as_int(v);
    const int y = __builtin_amdgcn_ds_swizzle(x, 0x101F);   // xor-4, and=0x1F
    return v + __int_as_float(y);
}

// dist slot s lives in the tile's dead pad columns (cols 16..19 of each
// TSTR=20 row; staging writes only cols 0..15, search/qv/refine read only
// cols <=15). flat index: (s>>2)*20 + 16 + (s&3). 243 slots <= 540 available.
static __device__ __forceinline__ int dist_addr(int s) {
    return (s >> 2) * TSTR + 16 + (s & 3);
}

// R17 structure (4 wave-local queries / 256-thread block, zero __syncthreads,
// TSTR=20, compile-time-plane staging, pk-packed search, s64 top-k, refine in
// regs). R18 delta: dists[] LDS deleted — overlaid into the tile pad columns
// -> per-block LDS 47104 -> ~43264 B (3 blocks/CU if the schedulable LDS pool
// is 128 KB). All math bit-identical to R17.
__global__ __launch_bounds__(256) void dnls_query_kernel(
    const float* __restrict__ noisy, const float* __restrict__ deno,
    const float* __restrict__ fflow, const float* __restrict__ bflow,
    const int* __restrict__ ep_ptr, float* __restrict__ partial)
{
    const int tid  = threadIdx.x;
    const int wid  = tid >> 6;
    const int lane = tid & 63;
    const int sub  = lane & 7;
    const int q    = blockIdx.x * 4 + wid;
    const int tqi  = q >> 12;
    const int r0   = q & 4095;
    const int hq   = (r0 >> 6) * STRIDE0;
    const int wq   = (r0 & 63) * STRIDE0;
    const int k_eff = k_eff_from_epoch(ep_ptr[0]);

    __shared__ __align__(16) float tile[4][9][15][TSTR];   // 43.2 KB total, pads host dists

    // --- centers (wave-uniform; flow loads broadcast) ---
    const size_t bfo = (size_t)(tqi * 2) * HW + (size_t)hq * WW + wq;
    const int ifdx = (int)rintf(fflow[bfo]);
    const int ifdy = (int)rintf(fflow[bfo + HW]);
    const int ibdx = (int)rintf(bflow[bfo]);
    const int ibdy = (int)rintf(bflow[bfo + HW]);
    const int tcA[3] = { tqi, max(tqi - 1, 0), min(tqi + 1, TT - 1) };
    const int hvA[3] = { hq, min(max(hq + ibdy, 0), HH - 1), min(max(hq + ifdy, 0), HH - 1) };
    const int wvA[3] = { wq, min(max(wq + ibdx, 0), WW - 1), min(max(wq + ifdx, 0), WW - 1) };

    // --- refine deno values straight to registers (consumed at the very end) ---
    const int li = lane / 7, lj = lane - (lane / 7) * 7;   // valid for lane<49
    float dpr[CC];
    {
        const float* db = deno + (size_t)(tqi * CC) * HW
                          + (size_t)min(hq + li, HH - 1) * WW + min(wq + lj, WW - 1);
        #pragma unroll
        for (int c = 0; c < CC; ++c) dpr[c] = (lane < 49) ? db[c * HW] : 0.f;
    }

    // --- staging: 9 plane-rounds, compile-time (dti,c); lanes<60 ---
    #pragma unroll
    for (int p = 0; p < 9; ++p) {
        const int dti = p / 3, c = p - dti * 3;            // compile-time
        const int tcv = tcA[dti], hcv = hvA[dti], wcv = wvA[dti];
        const int h0  = max(hcv - 4, 0), w0 = max(wcv - 4, 0);
        if (lane < 60) {
            const int row = lane >> 2, qd = lane & 3;
            const float* src = noisy + (size_t)(tcv * CC + c) * HW;
            f4a v;
            if (hcv <= HH - 11 && wcv <= WW - 12) {        // wave-uniform per plane
                v = (f4a)(*(const f4u*)(src + (h0 + row) * WW + w0 + qd * 4));
            } else {
                const int rrow = min(h0 + row, HH - 1);
                const float* sr = src + rrow * WW;
                #pragma unroll
                for (int t = 0; t < 4; ++t)
                    v[t] = sr[min(w0 + min(qd * 4 + t, 14), WW - 1)];
            }
            *(f4a*)&tile[wid][p][row][qd * 4] = v;
        }
    }
    __builtin_amdgcn_wave_barrier();   // order staging ds_writes before ds_reads

    float* const flat = &tile[wid][0][0][0];   // per-query flat view (2700 floats)

    // --- qv hoist: query patch row (i = sub) from tile[wid][0..2], bit-exact ---
    const int oh = min(hq, 4), ow = min(wq, 4);
    float qv[CC][8];
    #pragma unroll
    for (int c = 0; c < CC; ++c) {
        *(f4a*)&qv[c][0] = *(const f4a*)&tile[wid][c][oh + sub][ow];
        *(f4a*)&qv[c][4] = *(const f4a*)&tile[wid][c][oh + sub][ow + 4];
    }

    // --- search: 4 iterations x 8 groups; g=(dti,dh), lane sub = patch row i ---
    #pragma unroll
    for (int it = 0; it < 4; ++it) {
        const int g = it * 8 + (lane >> 3);
        if (g < 27) {
            const int dti = (g >= 18) ? 2 : (g >= 9 ? 1 : 0);
            const int dh  = g - 9 * dti;
            const int hcv = hvA[dti], wcv = wvA[dti];
            float acc[9];
            #pragma unroll
            for (int dw = 0; dw < 9; ++dw) acc[dw] = 0.f;
            if (sub < PS) {
                if (hcv >= 4 && wcv >= 4) {
                    // fast path, pk-packed: dw pairs (0,1)(2,3)(4,5)(6,7) + dw=8
                    const int r = dh + sub;
                    f2 a2[4] = { f2{0.f,0.f}, f2{0.f,0.f}, f2{0.f,0.f}, f2{0.f,0.f} };
                    float a8 = 0.f;
                    #pragma unroll
                    for (int c = 0; c < CC; ++c) {
                        const float* tp = &tile[wid][dti * 3 + c][r][0];
                        float tv[16];
                        *(f4a*)&tv[0]  = *(const f4a*)(tp);
                        *(f4a*)&tv[4]  = *(const f4a*)(tp + 4);
                        *(f4a*)&tv[8]  = *(const f4a*)(tp + 8);
                        *(f4a*)&tv[12] = *(const f4a*)(tp + 12);
                        #pragma unroll
                        for (int j = 0; j < 7; ++j) {
                            const float qj = qv[c][j];
                            #pragma unroll
                            for (int pp = 0; pp < 4; ++pp) {
                                f2 t; t[0] = tv[2 * pp + j]; t[1] = tv[2 * pp + 1 + j];
                                const f2 d = qj - t;                              // v_pk_add
                                a2[pp] = __builtin_elementwise_fma(d, d, a2[pp]); // v_pk_fma
                            }
                            const float ds = qj - tv[8 + j];
                            a8 = fmaf(ds, ds, a8);
                        }
                    }
                    #pragma unroll
                    for (int pp = 0; pp < 4; ++pp) { acc[2 * pp] = a2[pp][0]; acc[2 * pp + 1] = a2[pp][1]; }
                    acc[8] = a8;
                } else {
                    // top/left-edge centers: double clamp mapped into the tile
                    const int h0 = max(hcv - 4, 0), w0 = max(wcv - 4, 0);
                    const int hc = min(max(hcv + dh - 4, 0), HH - 1);
                    const int r  = min(hc + sub, HH - 1) - h0;
                    #pragma unroll
                    for (int c = 0; c < CC; ++c) {
                        const float* tp = &tile[wid][dti * 3 + c][r][0];
                        #pragma unroll
                        for (int dw = 0; dw < 9; ++dw) {
                            const int wc = min(max(wcv + dw - 4, 0), WW - 1);
                            #pragma unroll
                            for (int j = 0; j < 7; ++j) {
                                const int col = min(wc + j, WW - 1) - w0;
                                const float d = qv[c][j] - tp[col];
                                acc[dw] = fmaf(d, d, acc[dw]);
                            }
                        }
                    }
                }
            }
            // sum the 7 rows across the 8-lane segment (same tree as __shfl_xor)
            #pragma unroll
            for (int dw = 0; dw < 9; ++dw) {
                float v = acc[dw];
                v = dpp_add<0xB1>(v);   // xor 1
                v = dpp_add<0x4E>(v);   // xor 2
                v = swz4_add(v);        // xor 4
                acc[dw] = v;
            }
            if (sub == 0) {
                #pragma unroll
                for (int dw = 0; dw < 9; ++dw) flat[dist_addr(g * 9 + dw)] = acc[dw];
            }
        }
    }
    __builtin_amdgcn_wave_barrier();   // order dist writes before reads

    // --- top-k on packed s64 keys (bit-exact (dist, idx) lex order) ---
    s64 dk[4];
    #pragma unroll
    for (int kk = 0; kk < 4; ++kk) {
        const int n = lane + kk * 64;
        float v = (n < NOFF) ? flat[dist_addr(n)] : INFINITY;
        if (n == SELF_IDX) v = -INFINITY;
        dk[kk] = ((s64)__float_as_int(v) << 32) | (unsigned)n;
    }
    int seln[KMAX];
    #pragma unroll
    for (int k = 0; k < KMAX; ++k) {
        s64 b = dk[0];
        #pragma unroll
        for (int kk = 1; kk < 4; ++kk) if (dk[kk] < b) b = dk[kk];
        #pragma unroll
        for (int off = 32; off > 0; off >>= 1) {
            const s64 o = __shfl_xor(b, off);
            if (o < b) b = o;
        }
        seln[k] = (int)(unsigned)(b & 0xFFFFFFFFll);
        #pragma unroll
        for (int kk = 0; kk < 4; ++kk) if (dk[kk] == b) dk[kk] = 0x7FFFFFFFFFFFFFFFll;
    }

    // --- refine: per-k wave-uniform loop; lanes 0..48 = (i,j) of the patch ---
    float part = 0.f;
    #pragma unroll
    for (int k = 1; k < KMAX; ++k) {
        if (k < k_eff) {
            const int n = __builtin_amdgcn_readfirstlane(seln[k]);  // wave-uniform
            const int dti = (n >= 162) ? 2 : (n >= 81 ? 1 : 0);
            const int rr  = n - dti * 81;
            const int dh  = rr / 9;
            const int dw  = rr - dh * 9;
            const int hcv = hvA[dti], wcv = wvA[dti];
            const int h0  = max(hcv - 4, 0), w0 = max(wcv - 4, 0);
            const int hc  = min(max(hcv + dh - 4, 0), HH - 1);
            const int wc  = min(max(wcv + dw - 4, 0), WW - 1);
            if (lane < 49) {
                const int row = min(hc + li, HH - 1) - h0;
                const int col = min(wc + lj, WW - 1) - w0;
                #pragma unroll
                for (int c = 0; c < CC; ++c) {
                    const float d = dpr[c] - tile[wid][dti * 3 + c][row][col];
                    part = fmaf(d, d, part);
                }
            }
        }
    }

    #pragma unroll
    for (int off = 32; off > 0; off >>= 1) part += __shfl_xor(part, off);
    if (lane == 0) partial[q] = part;
}

__global__ __launch_bounds__(1024) void dnls_reduce_kernel(
    const float* __restrict__ partial, int n,
    const int* __restrict__ ep_ptr, float* __restrict__ out)
{
    const int tid = threadIdx.x;
    double acc = 0.0;
    for (int i = tid; i < n; i += 1024) acc += (double)partial[i];
    __shared__ double red[1024];
    red[tid] = acc;
    __syncthreads();
    for (int s = 512; s > 0; s >>= 1) {
        if (tid < s) red[tid] += red[tid + s];
        __syncthreads();
    }
    if (tid == 0) {
        const int k_eff = k_eff_from_epoch(ep_ptr[0]);
        out[0] = (float)(red[0] / ((double)n * (double)(k_eff - 1)));
    }
}

extern "C" void kernel_launch(void* const* d_in, const int* in_sizes, int n_in,
                              void* d_out, int out_size, void* d_ws, size_t ws_size,
                              hipStream_t stream) {
    const float* noisy = (const float*)d_in[0];
    const float* deno  = (const float*)d_in[1];
    const float* fflow = (const float*)d_in[2];
    const float* bflow = (const float*)d_in[3];
    const int*   ep    = (const int*)d_in[4];
    float* partial = (float*)d_ws;            // BB*QQ floats = 80 KB
    float* out = (float*)d_out;

    dnls_query_kernel<<<(BB * QQ) / 4, 256, 0, stream>>>(noisy, deno, fflow, bflow, ep, partial);
    dnls_reduce_kernel<<<1, 1024, 0, stream>>>(partial, BB * QQ, ep, out);
}

// Round 19
// 115.915 us; speedup vs baseline: 1.0261x; 1.0261x over previous
//
#include <hip/hip_runtime.h>

#define WS 9
#define PS 7
#define KMAX 10
#define STRIDE0 4
#define NEPOCHS 100
#define BB 1
#define TT 5
#define CC 3
#define HH 256
#define WW 256
#define QQ (TT * 64 * 64)             // 20480
#define NOFF 243
#define SELF_IDX 40                   // (WS/2)*WS + WS/2
#define HW (HH * WW)
#define TSTR 20                       // tile row stride: 80B = b128-aligned, conflict-free

typedef float f4a __attribute__((ext_vector_type(4)));              // aligned LDS/reg
typedef float f4u __attribute__((ext_vector_type(4), aligned(4)));  // 4B-aligned global
typedef float f2  __attribute__((ext_vector_type(2)));              // packed pair
typedef long long s64;

static __device__ __forceinline__ int k_eff_from_epoch(int ep) {
    int k = (int)((double)KMAX * ((double)(NEPOCHS - ep) / (double)NEPOCHS));
    return k < 2 ? 2 : k;
}

template <int CTRL>
static __device__ __forceinline__ float dpp_add(float v) {
    const int x = __float_as_int(v);
    const int y = __builtin_amdgcn_update_dpp(0, x, CTRL, 0xF, 0xF, true);
    return v + __int_as_float(y);
}
static __device__ __forceinline__ float swz4_add(float v) {
    const int x = __float_as_int(v);
    const int y = __builtin_amdgcn_ds_swizzle(x, 0x101F);   // xor-4, and=0x1F
    return v + __int_as_float(y);
}

// Best-measured configuration (R17, 116.06 us): 4 wave-local queries per
// 256-thread block, zero __syncthreads; staging = 9 plane-rounds with
// compile-time (dti,c); qv hoisted from tile[0] (bit-exact); search fast path
// pk-packed (v_pk_fma_f32, per-half IEEE == scalar); top-k on packed s64 keys
// ((dist_bits<<32)|n == (dist, idx) lex order bit-exactly); refine data in
// registers with wave-uniform per-k loop. Separate dists[] array (R18's
// pad-column overlay cost ~2.4% — reverted).
__global__ __launch_bounds__(256) void dnls_query_kernel(
    const float* __restrict__ noisy, const float* __restrict__ deno,
    const float* __restrict__ fflow, const float* __restrict__ bflow,
    const int* __restrict__ ep_ptr, float* __restrict__ partial)
{
    const int tid  = threadIdx.x;
    const int wid  = tid >> 6;
    const int lane = tid & 63;
    const int sub  = lane & 7;
    const int q    = blockIdx.x * 4 + wid;
    const int tqi  = q >> 12;
    const int r0   = q & 4095;
    const int hq   = (r0 >> 6) * STRIDE0;
    const int wq   = (r0 & 63) * STRIDE0;
    const int k_eff = k_eff_from_epoch(ep_ptr[0]);

    __shared__ __align__(16) float tile[4][9][15][TSTR];   // 43.2 KB ([dti*3+c] planes)
    __shared__ float dists[4][243];                        // 3.9 KB

    // --- centers (wave-uniform; flow loads broadcast) ---
    const size_t bfo = (size_t)(tqi * 2) * HW + (size_t)hq * WW + wq;
    const int ifdx = (int)rintf(fflow[bfo]);
    const int ifdy = (int)rintf(fflow[bfo + HW]);
    const int ibdx = (int)rintf(bflow[bfo]);
    const int ibdy = (int)rintf(bflow[bfo + HW]);
    const int tcA[3] = { tqi, max(tqi - 1, 0), min(tqi + 1, TT - 1) };
    const int hvA[3] = { hq, min(max(hq + ibdy, 0), HH - 1), min(max(hq + ifdy, 0), HH - 1) };
    const int wvA[3] = { wq, min(max(wq + ibdx, 0), WW - 1), min(max(wq + ifdx, 0), WW - 1) };

    // --- refine deno values straight to registers (consumed at the very end) ---
    const int li = lane / 7, lj = lane - (lane / 7) * 7;   // valid for lane<49
    float dpr[CC];
    {
        const float* db = deno + (size_t)(tqi * CC) * HW
                          + (size_t)min(hq + li, HH - 1) * WW + min(wq + lj, WW - 1);
        #pragma unroll
        for (int c = 0; c < CC; ++c) dpr[c] = (lane < 49) ? db[c * HW] : 0.f;
    }

    // --- staging: 9 plane-rounds, compile-time (dti,c); lanes<60 ---
    #pragma unroll
    for (int p = 0; p < 9; ++p) {
        const int dti = p / 3, c = p - dti * 3;            // compile-time
        const int tcv = tcA[dti], hcv = hvA[dti], wcv = wvA[dti];
        const int h0  = max(hcv - 4, 0), w0 = max(wcv - 4, 0);
        if (lane < 60) {
            const int row = lane >> 2, qd = lane & 3;
            const float* src = noisy + (size_t)(tcv * CC + c) * HW;
            f4a v;
            if (hcv <= HH - 11 && wcv <= WW - 12) {        // wave-uniform per plane
                v = (f4a)(*(const f4u*)(src + (h0 + row) * WW + w0 + qd * 4));
            } else {
                const int rrow = min(h0 + row, HH - 1);
                const float* sr = src + rrow * WW;
                #pragma unroll
                for (int t = 0; t < 4; ++t)
                    v[t] = sr[min(w0 + min(qd * 4 + t, 14), WW - 1)];
            }
            *(f4a*)&tile[wid][p][row][qd * 4] = v;
        }
    }
    __builtin_amdgcn_wave_barrier();   // order staging ds_writes before ds_reads

    // --- qv hoist: query patch row (i = sub) from tile[wid][0..2], bit-exact ---
    const int oh = min(hq, 4), ow = min(wq, 4);
    float qv[CC][8];
    #pragma unroll
    for (int c = 0; c < CC; ++c) {
        *(f4a*)&qv[c][0] = *(const f4a*)&tile[wid][c][oh + sub][ow];
        *(f4a*)&qv[c][4] = *(const f4a*)&tile[wid][c][oh + sub][ow + 4];
    }

    // --- search: 4 iterations x 8 groups; g=(dti,dh), lane sub = patch row i ---
    #pragma unroll
    for (int it = 0; it < 4; ++it) {
        const int g = it * 8 + (lane >> 3);
        if (g < 27) {
            const int dti = (g >= 18) ? 2 : (g >= 9 ? 1 : 0);
            const int dh  = g - 9 * dti;
            const int hcv = hvA[dti], wcv = wvA[dti];
            float acc[9];
            #pragma unroll
            for (int dw = 0; dw < 9; ++dw) acc[dw] = 0.f;
            if (sub < PS) {
                if (hcv >= 4 && wcv >= 4) {
                    // fast path, pk-packed: dw pairs (0,1)(2,3)(4,5)(6,7) + dw=8
                    const int r = dh + sub;
                    f2 a2[4] = { f2{0.f,0.f}, f2{0.f,0.f}, f2{0.f,0.f}, f2{0.f,0.f} };
                    float a8 = 0.f;
                    #pragma unroll
                    for (int c = 0; c < CC; ++c) {
                        const float* tp = &tile[wid][dti * 3 + c][r][0];
                        float tv[16];
                        *(f4a*)&tv[0]  = *(const f4a*)(tp);
                        *(f4a*)&tv[4]  = *(const f4a*)(tp + 4);
                        *(f4a*)&tv[8]  = *(const f4a*)(tp + 8);
                        *(f4a*)&tv[12] = *(const f4a*)(tp + 12);
                        #pragma unroll
                        for (int j = 0; j < 7; ++j) {
                            const float qj = qv[c][j];
                            #pragma unroll
                            for (int pp = 0; pp < 4; ++pp) {
                                f2 t; t[0] = tv[2 * pp + j]; t[1] = tv[2 * pp + 1 + j];
                                const f2 d = qj - t;                              // v_pk_add
                                a2[pp] = __builtin_elementwise_fma(d, d, a2[pp]); // v_pk_fma
                            }
                            const float ds = qj - tv[8 + j];
                            a8 = fmaf(ds, ds, a8);
                        }
                    }
                    #pragma unroll
                    for (int pp = 0; pp < 4; ++pp) { acc[2 * pp] = a2[pp][0]; acc[2 * pp + 1] = a2[pp][1]; }
                    acc[8] = a8;
                } else {
                    // top/left-edge centers: double clamp mapped into the tile
                    const int h0 = max(hcv - 4, 0), w0 = max(wcv - 4, 0);
                    const int hc = min(max(hcv + dh - 4, 0), HH - 1);
                    const int r  = min(hc + sub, HH - 1) - h0;
                    #pragma unroll
                    for (int c = 0; c < CC; ++c) {
                        const float* tp = &tile[wid][dti * 3 + c][r][0];
                        #pragma unroll
                        for (int dw = 0; dw < 9; ++dw) {
                            const int wc = min(max(wcv + dw - 4, 0), WW - 1);
                            #pragma unroll
                            for (int j = 0; j < 7; ++j) {
                                const int col = min(wc + j, WW - 1) - w0;
                                const float d = qv[c][j] - tp[col];
                                acc[dw] = fmaf(d, d, acc[dw]);
                            }
                        }
                    }
                }
            }
            // sum the 7 rows across the 8-lane segment (same tree as __shfl_xor)
            #pragma unroll
            for (int dw = 0; dw < 9; ++dw) {
                float v = acc[dw];
                v = dpp_add<0xB1>(v);   // xor 1
                v = dpp_add<0x4E>(v);   // xor 2
                v = swz4_add(v);        // xor 4
                acc[dw] = v;
            }
            if (sub == 0) {
                #pragma unroll
                for (int dw = 0; dw < 9; ++dw) dists[wid][g * 9 + dw] = acc[dw];
            }
        }
    }
    __builtin_amdgcn_wave_barrier();   // order dist writes before reads

    // --- top-k on packed s64 keys (bit-exact (dist, idx) lex order) ---
    const float* dq = dists[wid];
    s64 dk[4];
    #pragma unroll
    for (int kk = 0; kk < 4; ++kk) {
        const int n = lane + kk * 64;
        float v = (n < NOFF) ? dq[n] : INFINITY;
        if (n == SELF_IDX) v = -INFINITY;
        dk[kk] = ((s64)__float_as_int(v) << 32) | (unsigned)n;
    }
    int seln[KMAX];
    #pragma unroll
    for (int k = 0; k < KMAX; ++k) {
        s64 b = dk[0];
        #pragma unroll
        for (int kk = 1; kk < 4; ++kk) if (dk[kk] < b) b = dk[kk];
        #pragma unroll
        for (int off = 32; off > 0; off >>= 1) {
            const s64 o = __shfl_xor(b, off);
            if (o < b) b = o;
        }
        seln[k] = (int)(unsigned)(b & 0xFFFFFFFFll);
        #pragma unroll
        for (int kk = 0; kk < 4; ++kk) if (dk[kk] == b) dk[kk] = 0x7FFFFFFFFFFFFFFFll;
    }

    // --- refine: per-k wave-uniform loop; lanes 0..48 = (i,j) of the patch ---
    float part = 0.f;
    #pragma unroll
    for (int k = 1; k < KMAX; ++k) {
        if (k < k_eff) {
            const int n = __builtin_amdgcn_readfirstlane(seln[k]);  // wave-uniform
            const int dti = (n >= 162) ? 2 : (n >= 81 ? 1 : 0);
            const int rr  = n - dti * 81;
            const int dh  = rr / 9;
            const int dw  = rr - dh * 9;
            const int hcv = hvA[dti], wcv = wvA[dti];
            const int h0  = max(hcv - 4, 0), w0 = max(wcv - 4, 0);
            const int hc  = min(max(hcv + dh - 4, 0), HH - 1);
            const int wc  = min(max(wcv + dw - 4, 0), WW - 1);
            if (lane < 49) {
                const int row = min(hc + li, HH - 1) - h0;
                const int col = min(wc + lj, WW - 1) - w0;
                #pragma unroll
                for (int c = 0; c < CC; ++c) {
                    const float d = dpr[c] - tile[wid][dti * 3 + c][row][col];
                    part = fmaf(d, d, part);
                }
            }
        }
    }

    #pragma unroll
    for (int off = 32; off > 0; off >>= 1) part += __shfl_xor(part, off);
    if (lane == 0) partial[q] = part;
}

__global__ __launch_bounds__(1024) void dnls_reduce_kernel(
    const float* __restrict__ partial, int n,
    const int* __restrict__ ep_ptr, float* __restrict__ out)
{
    const int tid = threadIdx.x;
    double acc = 0.0;
    for (int i = tid; i < n; i += 1024) acc += (double)partial[i];
    __shared__ double red[1024];
    red[tid] = acc;
    __syncthreads();
    for (int s = 512; s > 0; s >>= 1) {
        if (tid < s) red[tid] += red[tid + s];
        __syncthreads();
    }
    if (tid == 0) {
        const int k_eff = k_eff_from_epoch(ep_ptr[0]);
        out[0] = (float)(red[0] / ((double)n * (double)(k_eff - 1)));
    }
}

extern "C" void kernel_launch(void* const* d_in, const int* in_sizes, int n_in,
                              void* d_out, int out_size, void* d_ws, size_t ws_size,
                              hipStream_t stream) {
    const float* noisy = (const float*)d_in[0];
    const float* deno  = (const float*)d_in[1];
    const float* fflow = (const float*)d_in[2];
    const float* bflow = (const float*)d_in[3];
    const int*   ep    = (const int*)d_in[4];
    float* partial = (float*)d_ws;            // BB*QQ floats = 80 KB
    float* out = (float*)d_out;

    dnls_query_kernel<<<(BB * QQ) / 4, 256, 0, stream>>>(noisy, deno, fflow, bflow, ep, partial);
    dnls_reduce_kernel<<<1, 1024, 0, stream>>>(partial, BB * QQ, ep, out);
}